// Round 11
// baseline (396.377 us; speedup 1.0000x reference)
//
#include <hip/hip_runtime.h>
#include <hip/hip_bf16.h>
#include <math.h>

#define D_MODEL 768
#define NHEADS  12
#define DHEAD   64
#define NQR     8     // query rows
#define BB      16    // batch (ranks)
#define PP      197   // tokens per rank
#define NPAIR   256   // BB*BB
#define MKV     (BB*PP)     // 3152
#define LN_EPSF 1e-5f
#define SCALEF  0.125f      // 64^-0.5

// split-bf16 K-extended GEMM params
#define KTOT  2304          // 3*768:  [a_hi|a_hi|a_lo] x [w_hi|w_lo|w_hi]
#define KSPLIT 3
#define KPER  (KTOT/KSPLIT) // 768
#define MPAD  3200          // 25*128
#define BM 128
#define BN 128
#define BK 64

#define CH0   100           // chunk 0: p in [0,100)
#define CH1   97            // chunk 1: p in [100,197)
#define CHMAX 100

typedef __attribute__((ext_vector_type(8))) short short8v;   // 8 bf16
typedef __attribute__((ext_vector_type(4))) float float4v;   // mfma acc

__device__ __forceinline__ void gload16(const void* g, void* l){
  __builtin_amdgcn_global_load_lds(
      (const __attribute__((address_space(1))) unsigned int*)g,
      (__attribute__((address_space(3))) unsigned int*)l, 16, 0, 0);
}

__device__ __forceinline__ float lane_bcast(float v, int src){
  return __int_as_float(__builtin_amdgcn_readlane(__float_as_int(v), src));
}

// ---------------------------------------------------------------------------
// prep: fused pack + q GEMM.  (unchanged)
// ---------------------------------------------------------------------------
__global__ __launch_bounds__(192) void prep_kernel(
    const float* __restrict__ kvx, const float* __restrict__ kvw,
    __hip_bfloat16* __restrict__ Ab, __hip_bfloat16* __restrict__ Wb,
    const float* __restrict__ qx, const float* __restrict__ qw,
    float* __restrict__ qy)
{
  __shared__ float xs[NQR*D_MODEL];
  int b = blockIdx.x, t = threadIdx.x;
  if (b < MPAD + D_MODEL){
    const float* X; __hip_bfloat16* Y; int valid, mode, m;
    if (b < MPAD){ X = kvx; Y = Ab; valid = MKV;     mode = 0; m = b; }
    else         { X = kvw; Y = Wb; valid = D_MODEL; mode = 1; m = b - MPAD; }
    int k = t*4;
    float4 v = (m < valid) ? *(const float4*)&X[(size_t)m*D_MODEL + k]
                           : make_float4(0.f,0.f,0.f,0.f);
    float xsv[4] = {v.x, v.y, v.z, v.w};
    unsigned short hu[4], lu[4];
    #pragma unroll
    for (int i = 0; i < 4; i++){
      __hip_bfloat16 h = __float2bfloat16(xsv[i]);
      float hf = __bfloat162float(h);
      __hip_bfloat16 l = __float2bfloat16(xsv[i] - hf);
      hu[i] = *(unsigned short*)&h;
      lu[i] = *(unsigned short*)&l;
    }
    ushort4 hv = {hu[0], hu[1], hu[2], hu[3]};
    ushort4 lv = {lu[0], lu[1], lu[2], lu[3]};
    ushort4* row = (ushort4*)(Y + (size_t)m*KTOT);
    int s = k >> 2;
    if (mode == 0){ row[s] = hv; row[s+192] = hv; row[s+384] = lv; }
    else          { row[s] = hv; row[s+192] = lv; row[s+384] = hv; }
    return;
  }
  // ---- q GEMM: block covers 6 output cols, 32 lanes each ----
  int b2 = b - (MPAD + D_MODEL);
  for (int e = t*4; e < NQR*D_MODEL; e += 768)
    *(float4*)&xs[e] = *(const float4*)&qx[e];
  __syncthreads();
  int col = t >> 5, lane = t & 31;
  int c = b2*6 + col;
  const float* wr = qw + (size_t)c*D_MODEL;
  float acc[NQR] = {};
  for (int k = lane*4; k < D_MODEL; k += 128){
    float4 w4 = *(const float4*)&wr[k];
    #pragma unroll
    for (int q = 0; q < NQR; q++){
      float4 x4 = *(const float4*)&xs[q*D_MODEL + k];
      acc[q] += x4.x*w4.x + x4.y*w4.y + x4.z*w4.z + x4.w*w4.w;
    }
  }
  #pragma unroll
  for (int q = 0; q < NQR; q++){
    float a = acc[q];
    for (int off = 16; off >= 1; off >>= 1) a += __shfl_xor(a, off, 32);
    if (lane == 0) qy[q*D_MODEL + c] = a;
  }
}

// ---------------------------------------------------------------------------
// bf16 MFMA GEMM: C[kt][m][n] partial over K-split (kt = 0..2).  (unchanged)
// ---------------------------------------------------------------------------
__global__ __launch_bounds__(256) void gemm_mfma_kernel(
    const __hip_bfloat16* __restrict__ Ab, const __hip_bfloat16* __restrict__ Wb,
    float* __restrict__ Cp)
{
  __shared__ __hip_bfloat16 As[BM*BK];   // 16 KB
  __shared__ __hip_bfloat16 Bs[BN*BK];   // 16 KB
  int tid = threadIdx.x;
  int wave = tid >> 6, lane = tid & 63;
  int m0 = blockIdx.x*BM, n0 = blockIdx.y*BN, kt = blockIdx.z;
  int wr = wave >> 1, wc = wave & 1;

  float4v acc[4][4];
  #pragma unroll
  for (int i = 0; i < 4; i++)
    #pragma unroll
    for (int j = 0; j < 4; j++)
      acc[i][j] = (float4v){0.f, 0.f, 0.f, 0.f};

  int sbase = wave*256;
  for (int st = 0; st < KPER/BK; ++st){
    int k0 = kt*KPER + st*BK;
    __syncthreads();
    #pragma unroll
    for (int i = 0; i < 4; i++){
      int s  = sbase + i*64 + lane;
      int r  = s >> 3, kg = s & 7;
      int kgg = kg ^ (r & 7);
      gload16(Ab + (size_t)(m0 + r)*KTOT + k0 + kgg*8, (char*)As + (size_t)s*16);
      gload16(Wb + (size_t)(n0 + r)*KTOT + k0 + kgg*8, (char*)Bs + (size_t)s*16);
    }
    __syncthreads();
    #pragma unroll
    for (int ks = 0; ks < 2; ks++){
      int kq = ks*4 + (lane >> 4);
      short8v af[4], bf[4];
      #pragma unroll
      for (int t = 0; t < 4; t++){
        int ar = wr*64 + t*16 + (lane & 15);
        int as_ = ar*8 + (kq ^ (ar & 7));
        af[t] = *(const short8v*)((const char*)As + (size_t)as_*16);
        int br = wc*64 + t*16 + (lane & 15);
        int bs_ = br*8 + (kq ^ (br & 7));
        bf[t] = *(const short8v*)((const char*)Bs + (size_t)bs_*16);
      }
      #pragma unroll
      for (int i = 0; i < 4; i++)
        #pragma unroll
        for (int j = 0; j < 4; j++)
          acc[i][j] = __builtin_amdgcn_mfma_f32_16x16x32_bf16(af[i], bf[j], acc[i][j], 0, 0, 0);
    }
  }

  float* C = Cp + (size_t)kt*MKV*D_MODEL;
  #pragma unroll
  for (int i = 0; i < 4; i++){
    int mb = m0 + wr*64 + i*16 + ((lane >> 4) << 2);
    #pragma unroll
    for (int j = 0; j < 4; j++){
      int n = n0 + wc*64 + j*16 + (lane & 15);
      #pragma unroll
      for (int r = 0; r < 4; r++){
        int m = mb + r;
        if (m < MKV) C[(size_t)m*D_MODEL + n] = acc[i][j][r];
      }
    }
  }
}

// ---------------------------------------------------------------------------
// ln_all: blocks [0,MKV) = kv rows, [MKV,MKV+8) = q rows.  (unchanged)
// ---------------------------------------------------------------------------
__global__ __launch_bounds__(256) void ln_all_kernel(
    const float* __restrict__ C0, const float* __restrict__ C1,
    const float* __restrict__ C2, const float* __restrict__ kv_b,
    const float* __restrict__ lnkv_w, const float* __restrict__ lnkv_b,
    float* __restrict__ kv_ln,
    const float* __restrict__ q_y, const float* __restrict__ q_b,
    const float* __restrict__ lnq_w, const float* __restrict__ lnq_b,
    float* __restrict__ q_ln)
{
  __shared__ float red[256], red2[256];
  int b = blockIdx.x, tid = threadIdx.x;
  const float *xa, *xb, *xc, *bias, *lw, *lb; float* outp; bool three;
  if (b < MKV){
    xa = C0 + (size_t)b*D_MODEL; xb = C1 + (size_t)b*D_MODEL;
    xc = C2 + (size_t)b*D_MODEL;
    bias = kv_b; lw = lnkv_w; lb = lnkv_b;
    outp = kv_ln + (size_t)b*D_MODEL; three = true;
  } else {
    int r = b - MKV;
    xa = q_y + (size_t)r*D_MODEL; xb = xa; xc = xa;
    bias = q_b; lw = lnq_w; lb = lnq_b;
    outp = q_ln + (size_t)r*D_MODEL; three = false;
  }
  float x0 = xa[tid      ] + (three ? xb[tid      ] + xc[tid      ] : 0.f) + bias[tid      ];
  float x1 = xa[tid + 256] + (three ? xb[tid + 256] + xc[tid + 256] : 0.f) + bias[tid + 256];
  float x2 = xa[tid + 512] + (three ? xb[tid + 512] + xc[tid + 512] : 0.f) + bias[tid + 512];
  red[tid] = x0 + x1 + x2; red2[tid] = x0*x0 + x1*x1 + x2*x2;
  __syncthreads();
  for (int st = 128; st > 0; st >>= 1){
    if (tid < st){ red[tid] += red[tid+st]; red2[tid] += red2[tid+st]; }
    __syncthreads();
  }
  float mean = red[0]*(1.f/768.f);
  float var  = red2[0]*(1.f/768.f) - mean*mean;
  float inv  = rsqrtf(var + LN_EPSF);
  outp[tid      ] = (x0-mean)*inv*lw[tid      ] + lb[tid      ];
  outp[tid + 256] = (x1-mean)*inv*lw[tid + 256] + lb[tid + 256];
  outp[tid + 512] = (x2-mean)*inv*lw[tid + 512] + lb[tid + 512];
}

// ---------------------------------------------------------------------------
// rank_proj v3: per (r, h, half) block, 512 threads = 8 waves, 1 q per wave.
// 12 waves/CU resident (vs 6 in R10) -- latency-hiding was the R10 limiter
// (VALUBusy 20%, Occ 12.8%).  U-loop fully unrolled (chunk sizes are
// compile-time) so readlane indices are immediates; 4 independent
// accumulators break the fma chain.  A stride-65 (proven conflict-free).
// ---------------------------------------------------------------------------
__global__ __launch_bounds__(512) void rank_proj_kernel(
    const float* __restrict__ kv_ln, const float* __restrict__ q_ln,
    const float* __restrict__ ppe, const float* __restrict__ ow,
    float* __restrict__ z1O, float* __restrict__ z2O,
    float* __restrict__ p1, float* __restrict__ p2)
{
  __shared__ float A[CHMAX*65];    // 26 KB
  __shared__ float Us[NQR*64];     //  2 KB
  int r = blockIdx.x, h = blockIdx.y, half = blockIdx.z;
  int tid = threadIdx.x;
  int wave = tid >> 6, lane = tid & 63;   // wave == q row
  const float* qrow = q_ln + (size_t)wave*D_MODEL + h*64;

  float u[4] = {0.f, 0.f, 0.f, 0.f};      // U[q][d=lane], 4-way split chain
  float z = 0.f;

  #pragma unroll
  for (int c = 0; c < 2; c++){
    const int p0 = c ? CH0 : 0;
    const int np = c ? CH1 : CH0;         // compile-time per c
    __syncthreads();                      // prior chunk A reads done
    for (int e = tid; e < np*16; e += 512){
      int p = e >> 4, dq = (e & 15) << 2;
      float4 a = *(const float4*)&kv_ln[((size_t)(r*PP + p0 + p))*D_MODEL + h*64 + dq];
      float4 b = *(const float4*)&ppe[((size_t)(half*PP + p0 + p))*D_MODEL + h*64 + dq];
      float* rw = &A[p*65 + dq];
      rw[0] = a.x + b.x; rw[1] = a.y + b.y;
      rw[2] = a.z + b.z; rw[3] = a.w + b.w;
    }
    __syncthreads();

    // scores for q=wave: slots p=lane (<97, always valid) and p=lane+64
    int p1v = lane + 64;
    bool v1 = p1v < np;
    int p1c = v1 ? p1v : 0;
    float s0 = 0.f, s1 = 0.f;
    for (int d = 0; d < 64; d++){
      float qv = qrow[d];                 // wave-uniform scalar load (L1)
      s0 += qv * A[lane*65 + d];
      s1 += qv * A[p1c*65 + d];
    }
    float e0 = __expf(s0*SCALEF);
    float e1 = v1 ? __expf(s1*SCALEF) : 0.f;
    z += e0 + e1;

    // U: e broadcast via readlane with IMMEDIATE index (loops unrolled)
    #pragma unroll
    for (int p = 0; p < 64; p++)
      u[p & 3] += lane_bcast(e0, p) * A[p*65 + lane];
    if (c == 0){
      #pragma unroll
      for (int p = 64; p < 100; p++)
        u[p & 3] += lane_bcast(e1, p - 64) * A[p*65 + lane];
    } else {
      #pragma unroll
      for (int p = 64; p < 97; p++)
        u[p & 3] += lane_bcast(e1, p - 64) * A[p*65 + lane];
    }
  }

  for (int off = 32; off >= 1; off >>= 1)
    z += __shfl_xor(z, off);
  float* zO = half ? z2O : z1O;
  if (lane == 0) zO[(r*NHEADS + h)*NQR + wave] = z;
  Us[wave*64 + lane] = u[0] + u[1] + u[2] + u[3];
  __syncthreads();

  // projection: thread covers n = tid (all) and n = tid+512 (waves 0-3)
  bool two = tid < 256;
  int n1 = tid + 512;
  float acc0[NQR] = {}, acc1[NQR] = {};
  const float* owh = ow + h*64;
  for (int d4 = 0; d4 < 64; d4 += 4){
    float4 w0 = *(const float4*)&owh[(size_t)tid*D_MODEL + d4];
    float4 w1 = two ? *(const float4*)&owh[(size_t)n1*D_MODEL + d4]
                    : make_float4(0.f,0.f,0.f,0.f);
    #pragma unroll
    for (int m = 0; m < NQR; m++){
      float4 uu = *(const float4*)&Us[m*64 + d4];
      acc0[m] += uu.x*w0.x + uu.y*w0.y + uu.z*w0.z + uu.w*w0.w;
      acc1[m] += uu.x*w1.x + uu.y*w1.y + uu.z*w1.z + uu.w*w1.w;
    }
  }
  float* P = half ? p2 : p1;
  #pragma unroll
  for (int m = 0; m < NQR; m++){
    size_t obase = (((size_t)r*NHEADS + h)*NQR + m)*D_MODEL;
    P[obase + tid] = acc0[m];
    if (two) P[obase + n1] = acc1[m];
  }
}

// ---------------------------------------------------------------------------
// Final combine: grid (i=16, q=8, jq=4), 192 thr; 4 j's per block. (unchanged)
// ---------------------------------------------------------------------------
__global__ __launch_bounds__(192) void combine_out_kernel(
    const float* __restrict__ z1, const float* __restrict__ z2,
    const float* __restrict__ p1, const float* __restrict__ p2,
    const float* __restrict__ out_b, float* __restrict__ out)
{
  __shared__ float cs[4][NHEADS];
  int i = blockIdx.x, q = blockIdx.y, jq = blockIdx.z;
  int j0 = jq*4;
  int tid = threadIdx.x;
  if (tid < 4*NHEADS){
    int j = tid / NHEADS, h = tid % NHEADS;
    int ii = (i*NHEADS + h)*NQR + q;
    int jj = ((j0 + j)*NHEADS + h)*NQR + q;
    cs[j][h] = 1.f / (z1[ii] + z2[jj]);
  }
  __syncthreads();

  int n4 = tid*4;
  float4 bv = *(const float4*)&out_b[n4];
  float4 acc[4];
  #pragma unroll
  for (int j = 0; j < 4; j++) acc[j] = bv;

  #pragma unroll
  for (int h = 0; h < NHEADS; h++){
    float4 a = *(const float4*)&p1[(((size_t)i*NHEADS + h)*NQR + q)*D_MODEL + n4];
    #pragma unroll
    for (int j = 0; j < 4; j++){
      float4 b = *(const float4*)&p2[(((size_t)(j0+j)*NHEADS + h)*NQR + q)*D_MODEL + n4];
      float c = cs[j][h];
      acc[j].x += c*(a.x - b.x);
      acc[j].y += c*(a.y - b.y);
      acc[j].z += c*(a.z - b.z);
      acc[j].w += c*(a.w - b.w);
    }
  }
  #pragma unroll
  for (int j = 0; j < 4; j++){
    int pair = i*BB + j0 + j;
    *(float4*)&out[((size_t)(pair*NQR + q))*D_MODEL + n4] = acc[j];
  }
}

// ---------------------------------------------------------------------------
extern "C" void kernel_launch(void* const* d_in, const int* in_sizes, int n_in,
                              void* d_out, int out_size, void* d_ws, size_t ws_size,
                              hipStream_t stream)
{
  const float* q_x    = (const float*)d_in[0];
  const float* kv_x   = (const float*)d_in[1];
  const float* ppe    = (const float*)d_in[2];
  const float* q_w    = (const float*)d_in[3];
  const float* q_b    = (const float*)d_in[4];
  const float* kv_w   = (const float*)d_in[5];
  const float* kv_b   = (const float*)d_in[6];
  const float* out_w  = (const float*)d_in[7];
  const float* out_b  = (const float*)d_in[8];
  const float* lnq_w  = (const float*)d_in[9];
  const float* lnq_b  = (const float*)d_in[10];
  const float* lnkv_w = (const float*)d_in[11];
  const float* lnkv_b = (const float*)d_in[12];
  float* out = (float*)d_out;

  float* ws    = (float*)d_ws;
  float* q_y   = ws;                              //  6144
  float* q_ln  = q_y  + NQR*D_MODEL;              //  6144
  float* Abuf_f = q_ln + NQR*D_MODEL;             //  3,686,400 (3200*2304 bf16)
  float* Wbuf_f = Abuf_f + (size_t)MPAD*KTOT/2;   //    884,736 (768*2304 bf16)
  float* C0    = Wbuf_f + (size_t)D_MODEL*KTOT/2; //  3x 2,420,736
  float* C1    = C0 + (size_t)MKV*D_MODEL;
  float* C2    = C1 + (size_t)MKV*D_MODEL;

  __hip_bfloat16* Abuf = (__hip_bfloat16*)Abuf_f;
  __hip_bfloat16* Wbuf = (__hip_bfloat16*)Wbuf_f;

  float* kv_ln = Abuf_f;                          // alias
  float* z1    = Wbuf_f;                          // alias
  float* z2    = z1 + BB*NHEADS*NQR;
  float* p1    = C0;                              // alias
  float* p2    = p1 + (size_t)BB*NHEADS*NQR*D_MODEL;

  prep_kernel<<<MPAD + D_MODEL + 128, 192, 0, stream>>>(
      kv_x, kv_w, Abuf, Wbuf, q_x, q_w, q_y);

  gemm_mfma_kernel<<<dim3(MPAD/BM, D_MODEL/BN, KSPLIT), 256, 0, stream>>>(
      Abuf, Wbuf, C0);

  ln_all_kernel<<<MKV + NQR, 256, 0, stream>>>(
      C0, C1, C2, kv_b, lnkv_w, lnkv_b, kv_ln,
      q_y, q_b, lnq_w, lnq_b, q_ln);

  rank_proj_kernel<<<dim3(BB, NHEADS, 2), 512, 0, stream>>>(
      kv_ln, q_ln, ppe, out_w, z1, z2, p1, p2);

  combine_out_kernel<<<dim3(BB, NQR, 4), 192, 0, stream>>>(
      z1, z2, p1, p2, out_b, out);
}

// Round 12
// 172.735 us; speedup vs baseline: 2.2947x; 2.2947x over previous
//
#include <hip/hip_runtime.h>
#include <hip/hip_bf16.h>
#include <math.h>

#define D_MODEL 768
#define NHEADS  12
#define DHEAD   64
#define NQR     8     // query rows
#define BB      16    // batch (ranks)
#define PP      197   // tokens per rank
#define NPAIR   256   // BB*BB
#define MKV     (BB*PP)     // 3152
#define LN_EPSF 1e-5f
#define SCALEF  0.125f      // 64^-0.5

// split-bf16 K-extended GEMM params
#define KTOT  2304          // 3*768:  [a_hi|a_hi|a_lo] x [w_hi|w_lo|w_hi]
#define KSPLIT 3
#define KPER  (KTOT/KSPLIT) // 768
#define MPAD  3200          // 25*128
#define BM 128
#define BN 128
#define BK 64

#define CH0   100           // chunk 0: p in [0,100)
#define CH1   97            // chunk 1: p in [100,197)
#define CHMAX 100
#define NIDX  (BB*NHEADS*2*NQR)   // 3072 (r,h,half,q) slots

typedef __attribute__((ext_vector_type(8))) short short8v;   // 8 bf16
typedef __attribute__((ext_vector_type(4))) float float4v;   // mfma acc

__device__ __forceinline__ void gload16(const void* g, void* l){
  __builtin_amdgcn_global_load_lds(
      (const __attribute__((address_space(1))) unsigned int*)g,
      (__attribute__((address_space(3))) unsigned int*)l, 16, 0, 0);
}

__device__ __forceinline__ float lane_bcast(float v, int src){
  return __int_as_float(__builtin_amdgcn_readlane(__float_as_int(v), src));
}

// ---------------------------------------------------------------------------
// prep: fused pack + q GEMM.  (unchanged)
// ---------------------------------------------------------------------------
__global__ __launch_bounds__(192) void prep_kernel(
    const float* __restrict__ kvx, const float* __restrict__ kvw,
    __hip_bfloat16* __restrict__ Ab, __hip_bfloat16* __restrict__ Wb,
    const float* __restrict__ qx, const float* __restrict__ qw,
    float* __restrict__ qy)
{
  __shared__ float xs[NQR*D_MODEL];
  int b = blockIdx.x, t = threadIdx.x;
  if (b < MPAD + D_MODEL){
    const float* X; __hip_bfloat16* Y; int valid, mode, m;
    if (b < MPAD){ X = kvx; Y = Ab; valid = MKV;     mode = 0; m = b; }
    else         { X = kvw; Y = Wb; valid = D_MODEL; mode = 1; m = b - MPAD; }
    int k = t*4;
    float4 v = (m < valid) ? *(const float4*)&X[(size_t)m*D_MODEL + k]
                           : make_float4(0.f,0.f,0.f,0.f);
    float xsv[4] = {v.x, v.y, v.z, v.w};
    unsigned short hu[4], lu[4];
    #pragma unroll
    for (int i = 0; i < 4; i++){
      __hip_bfloat16 h = __float2bfloat16(xsv[i]);
      float hf = __bfloat162float(h);
      __hip_bfloat16 l = __float2bfloat16(xsv[i] - hf);
      hu[i] = *(unsigned short*)&h;
      lu[i] = *(unsigned short*)&l;
    }
    ushort4 hv = {hu[0], hu[1], hu[2], hu[3]};
    ushort4 lv = {lu[0], lu[1], lu[2], lu[3]};
    ushort4* row = (ushort4*)(Y + (size_t)m*KTOT);
    int s = k >> 2;
    if (mode == 0){ row[s] = hv; row[s+192] = hv; row[s+384] = lv; }
    else          { row[s] = hv; row[s+192] = lv; row[s+384] = hv; }
    return;
  }
  // ---- q GEMM: block covers 6 output cols, 32 lanes each ----
  int b2 = b - (MPAD + D_MODEL);
  for (int e = t*4; e < NQR*D_MODEL; e += 768)
    *(float4*)&xs[e] = *(const float4*)&qx[e];
  __syncthreads();
  int col = t >> 5, lane = t & 31;
  int c = b2*6 + col;
  const float* wr = qw + (size_t)c*D_MODEL;
  float acc[NQR] = {};
  for (int k = lane*4; k < D_MODEL; k += 128){
    float4 w4 = *(const float4*)&wr[k];
    #pragma unroll
    for (int q = 0; q < NQR; q++){
      float4 x4 = *(const float4*)&xs[q*D_MODEL + k];
      acc[q] += x4.x*w4.x + x4.y*w4.y + x4.z*w4.z + x4.w*w4.w;
    }
  }
  #pragma unroll
  for (int q = 0; q < NQR; q++){
    float a = acc[q];
    for (int off = 16; off >= 1; off >>= 1) a += __shfl_xor(a, off, 32);
    if (lane == 0) qy[q*D_MODEL + c] = a;
  }
}

// ---------------------------------------------------------------------------
// bf16 MFMA GEMM: C[kt][m][n] partial over K-split (kt = 0..2).  (unchanged)
// ---------------------------------------------------------------------------
__global__ __launch_bounds__(256) void gemm_mfma_kernel(
    const __hip_bfloat16* __restrict__ Ab, const __hip_bfloat16* __restrict__ Wb,
    float* __restrict__ Cp)
{
  __shared__ __hip_bfloat16 As[BM*BK];   // 16 KB
  __shared__ __hip_bfloat16 Bs[BN*BK];   // 16 KB
  int tid = threadIdx.x;
  int wave = tid >> 6, lane = tid & 63;
  int m0 = blockIdx.x*BM, n0 = blockIdx.y*BN, kt = blockIdx.z;
  int wr = wave >> 1, wc = wave & 1;

  float4v acc[4][4];
  #pragma unroll
  for (int i = 0; i < 4; i++)
    #pragma unroll
    for (int j = 0; j < 4; j++)
      acc[i][j] = (float4v){0.f, 0.f, 0.f, 0.f};

  int sbase = wave*256;
  for (int st = 0; st < KPER/BK; ++st){
    int k0 = kt*KPER + st*BK;
    __syncthreads();
    #pragma unroll
    for (int i = 0; i < 4; i++){
      int s  = sbase + i*64 + lane;
      int r  = s >> 3, kg = s & 7;
      int kgg = kg ^ (r & 7);
      gload16(Ab + (size_t)(m0 + r)*KTOT + k0 + kgg*8, (char*)As + (size_t)s*16);
      gload16(Wb + (size_t)(n0 + r)*KTOT + k0 + kgg*8, (char*)Bs + (size_t)s*16);
    }
    __syncthreads();
    #pragma unroll
    for (int ks = 0; ks < 2; ks++){
      int kq = ks*4 + (lane >> 4);
      short8v af[4], bf[4];
      #pragma unroll
      for (int t = 0; t < 4; t++){
        int ar = wr*64 + t*16 + (lane & 15);
        int as_ = ar*8 + (kq ^ (ar & 7));
        af[t] = *(const short8v*)((const char*)As + (size_t)as_*16);
        int br = wc*64 + t*16 + (lane & 15);
        int bs_ = br*8 + (kq ^ (br & 7));
        bf[t] = *(const short8v*)((const char*)Bs + (size_t)bs_*16);
      }
      #pragma unroll
      for (int i = 0; i < 4; i++)
        #pragma unroll
        for (int j = 0; j < 4; j++)
          acc[i][j] = __builtin_amdgcn_mfma_f32_16x16x32_bf16(af[i], bf[j], acc[i][j], 0, 0, 0);
    }
  }

  float* C = Cp + (size_t)kt*MKV*D_MODEL;
  #pragma unroll
  for (int i = 0; i < 4; i++){
    int mb = m0 + wr*64 + i*16 + ((lane >> 4) << 2);
    #pragma unroll
    for (int j = 0; j < 4; j++){
      int n = n0 + wc*64 + j*16 + (lane & 15);
      #pragma unroll
      for (int r = 0; r < 4; r++){
        int m = mb + r;
        if (m < MKV) C[(size_t)m*D_MODEL + n] = acc[i][j][r];
      }
    }
  }
}

// ---------------------------------------------------------------------------
// ln_all: blocks [0,MKV) = kv rows, [MKV,MKV+8) = q rows.  (unchanged)
// ---------------------------------------------------------------------------
__global__ __launch_bounds__(256) void ln_all_kernel(
    const float* __restrict__ C0, const float* __restrict__ C1,
    const float* __restrict__ C2, const float* __restrict__ kv_b,
    const float* __restrict__ lnkv_w, const float* __restrict__ lnkv_b,
    float* __restrict__ kv_ln,
    const float* __restrict__ q_y, const float* __restrict__ q_b,
    const float* __restrict__ lnq_w, const float* __restrict__ lnq_b,
    float* __restrict__ q_ln)
{
  __shared__ float red[256], red2[256];
  int b = blockIdx.x, tid = threadIdx.x;
  const float *xa, *xb, *xc, *bias, *lw, *lb; float* outp; bool three;
  if (b < MKV){
    xa = C0 + (size_t)b*D_MODEL; xb = C1 + (size_t)b*D_MODEL;
    xc = C2 + (size_t)b*D_MODEL;
    bias = kv_b; lw = lnkv_w; lb = lnkv_b;
    outp = kv_ln + (size_t)b*D_MODEL; three = true;
  } else {
    int r = b - MKV;
    xa = q_y + (size_t)r*D_MODEL; xb = xa; xc = xa;
    bias = q_b; lw = lnq_w; lb = lnq_b;
    outp = q_ln + (size_t)r*D_MODEL; three = false;
  }
  float x0 = xa[tid      ] + (three ? xb[tid      ] + xc[tid      ] : 0.f) + bias[tid      ];
  float x1 = xa[tid + 256] + (three ? xb[tid + 256] + xc[tid + 256] : 0.f) + bias[tid + 256];
  float x2 = xa[tid + 512] + (three ? xb[tid + 512] + xc[tid + 512] : 0.f) + bias[tid + 512];
  red[tid] = x0 + x1 + x2; red2[tid] = x0*x0 + x1*x1 + x2*x2;
  __syncthreads();
  for (int st = 128; st > 0; st >>= 1){
    if (tid < st){ red[tid] += red[tid+st]; red2[tid] += red2[tid+st]; }
    __syncthreads();
  }
  float mean = red[0]*(1.f/768.f);
  float var  = red2[0]*(1.f/768.f) - mean*mean;
  float inv  = rsqrtf(var + LN_EPSF);
  outp[tid      ] = (x0-mean)*inv*lw[tid      ] + lb[tid      ];
  outp[tid + 256] = (x1-mean)*inv*lw[tid + 256] + lb[tid + 256];
  outp[tid + 512] = (x2-mean)*inv*lw[tid + 512] + lb[tid + 512];
}

// ---------------------------------------------------------------------------
// rank_chunk: R10's proven 256-thread body, split over p-chunks across blocks.
// grid (16, 12, 4): z = half*2 + c.  Max-free softmax => chunk partials merge
// by PURE SUM (no max/rescale).  Writes zC[c][idx], UC[c][idx][64].
// 96-VGPR class body (R11 lesson: no 512-thr full-unroll -> spill).
// ---------------------------------------------------------------------------
__global__ __launch_bounds__(256) void rank_chunk_kernel(
    const float* __restrict__ kv_ln, const float* __restrict__ q_ln,
    const float* __restrict__ ppe,
    float* __restrict__ zC, float* __restrict__ UC)
{
  __shared__ float A[CHMAX*65];    // 26 KB, stride 65 (conflict-free)
  int r = blockIdx.x, h = blockIdx.y;
  int half = blockIdx.z >> 1, c = blockIdx.z & 1;
  int p0 = c ? CH0 : 0;
  int np = c ? CH1 : CH0;
  int tid = threadIdx.x;
  int wave = tid >> 6, lane = tid & 63;
  int qa = 2*wave, qb = qa + 1;
  const float* qrowA = q_ln + (size_t)qa*D_MODEL + h*64;
  const float* qrowB = q_ln + (size_t)qb*D_MODEL + h*64;

  for (int e = tid; e < np*16; e += 256){
    int p = e >> 4, dq = (e & 15) << 2;
    float4 a = *(const float4*)&kv_ln[((size_t)(r*PP + p0 + p))*D_MODEL + h*64 + dq];
    float4 b = *(const float4*)&ppe[((size_t)(half*PP + p0 + p))*D_MODEL + h*64 + dq];
    float* rw = &A[p*65 + dq];
    rw[0] = a.x + b.x; rw[1] = a.y + b.y;
    rw[2] = a.z + b.z; rw[3] = a.w + b.w;
  }
  __syncthreads();

  // scores: slot0 p=lane (<97<=np always valid), slot1 p=lane+64
  int p1v = lane + 64;
  bool v1 = p1v < np;
  int p1c = v1 ? p1v : 0;
  float s0a = 0.f, s0b = 0.f, s1a = 0.f, s1b = 0.f;
  for (int d = 0; d < 64; d++){
    float qva = qrowA[d];
    float qvb = qrowB[d];
    float a0 = A[lane*65 + d];
    float a1 = A[p1c*65 + d];
    s0a += qva*a0; s1a += qva*a1;
    s0b += qvb*a0; s1b += qvb*a1;
  }
  float e0a = __expf(s0a*SCALEF);
  float e0b = __expf(s0b*SCALEF);
  float e1a = v1 ? __expf(s1a*SCALEF) : 0.f;
  float e1b = v1 ? __expf(s1b*SCALEF) : 0.f;
  float za = e0a + e1a;
  float zb = e0b + e1b;

  // U accumulation: broadcast e via readlane (runtime idx, R10-proven)
  float ua = 0.f, ub = 0.f;
  for (int p = 0; p < 64; p++){
    float av = A[p*65 + lane];
    ua += lane_bcast(e0a, p) * av;
    ub += lane_bcast(e0b, p) * av;
  }
  for (int p = 64; p < np; p++){
    float av = A[p*65 + lane];
    ua += lane_bcast(e1a, p - 64) * av;
    ub += lane_bcast(e1b, p - 64) * av;
  }

  for (int off = 32; off >= 1; off >>= 1){
    za += __shfl_xor(za, off);
    zb += __shfl_xor(zb, off);
  }
  int idxa = ((r*NHEADS + h)*2 + half)*NQR + qa;
  int idxb = idxa + 1;
  if (lane == 0){
    zC[c*NIDX + idxa] = za;
    zC[c*NIDX + idxb] = zb;
  }
  UC[((size_t)(c*NIDX + idxa))*64 + lane] = ua;
  UC[((size_t)(c*NIDX + idxb))*64 + lane] = ub;
}

// ---------------------------------------------------------------------------
// merge_proj: grid (16, 12, 2), 256 thr.  U = U_c0 + U_c1 (pure sum),
// z likewise; then R10's projection phase verbatim.
// ---------------------------------------------------------------------------
__global__ __launch_bounds__(256) void merge_proj_kernel(
    const float* __restrict__ zC, const float* __restrict__ UC,
    const float* __restrict__ ow,
    float* __restrict__ z1O, float* __restrict__ z2O,
    float* __restrict__ p1, float* __restrict__ p2)
{
  __shared__ float Us[NQR*64];
  int r = blockIdx.x, h = blockIdx.y, half = blockIdx.z;
  int tid = threadIdx.x;
  int base = ((r*NHEADS + h)*2 + half)*NQR;

  for (int e = tid; e < NQR*64; e += 256)
    Us[e] = UC[(size_t)base*64 + e] + UC[((size_t)NIDX + base)*64 + e];
  if (tid < NQR){
    float z = zC[base + tid] + zC[NIDX + base + tid];
    float* zO = half ? z2O : z1O;
    zO[(r*NHEADS + h)*NQR + tid] = z;
  }
  __syncthreads();

  float acc[NQR][3];
  #pragma unroll
  for (int m = 0; m < NQR; m++){ acc[m][0]=0.f; acc[m][1]=0.f; acc[m][2]=0.f; }
  const float* owh = ow + h*64;
  for (int d4 = 0; d4 < 64; d4 += 4){
    float4 w0 = *(const float4*)&owh[(size_t)(tid      )*D_MODEL + d4];
    float4 w1 = *(const float4*)&owh[(size_t)(tid + 256)*D_MODEL + d4];
    float4 w2 = *(const float4*)&owh[(size_t)(tid + 512)*D_MODEL + d4];
    #pragma unroll
    for (int m = 0; m < NQR; m++){
      float4 u = *(const float4*)&Us[m*64 + d4];
      acc[m][0] += u.x*w0.x + u.y*w0.y + u.z*w0.z + u.w*w0.w;
      acc[m][1] += u.x*w1.x + u.y*w1.y + u.z*w1.z + u.w*w1.w;
      acc[m][2] += u.x*w2.x + u.y*w2.y + u.z*w2.z + u.w*w2.w;
    }
  }
  float* P = half ? p2 : p1;
  #pragma unroll
  for (int m = 0; m < NQR; m++){
    size_t obase = (((size_t)r*NHEADS + h)*NQR + m)*D_MODEL;
    #pragma unroll
    for (int j = 0; j < 3; j++)
      P[obase + tid + 256*j] = acc[m][j];
  }
}

// ---------------------------------------------------------------------------
// Final combine: grid (i=16, q=8, jq=4), 192 thr; 4 j's per block. (unchanged)
// ---------------------------------------------------------------------------
__global__ __launch_bounds__(192) void combine_out_kernel(
    const float* __restrict__ z1, const float* __restrict__ z2,
    const float* __restrict__ p1, const float* __restrict__ p2,
    const float* __restrict__ out_b, float* __restrict__ out)
{
  __shared__ float cs[4][NHEADS];
  int i = blockIdx.x, q = blockIdx.y, jq = blockIdx.z;
  int j0 = jq*4;
  int tid = threadIdx.x;
  if (tid < 4*NHEADS){
    int j = tid / NHEADS, h = tid % NHEADS;
    int ii = (i*NHEADS + h)*NQR + q;
    int jj = ((j0 + j)*NHEADS + h)*NQR + q;
    cs[j][h] = 1.f / (z1[ii] + z2[jj]);
  }
  __syncthreads();

  int n4 = tid*4;
  float4 bv = *(const float4*)&out_b[n4];
  float4 acc[4];
  #pragma unroll
  for (int j = 0; j < 4; j++) acc[j] = bv;

  #pragma unroll
  for (int h = 0; h < NHEADS; h++){
    float4 a = *(const float4*)&p1[(((size_t)i*NHEADS + h)*NQR + q)*D_MODEL + n4];
    #pragma unroll
    for (int j = 0; j < 4; j++){
      float4 b = *(const float4*)&p2[(((size_t)(j0+j)*NHEADS + h)*NQR + q)*D_MODEL + n4];
      float c = cs[j][h];
      acc[j].x += c*(a.x - b.x);
      acc[j].y += c*(a.y - b.y);
      acc[j].z += c*(a.z - b.z);
      acc[j].w += c*(a.w - b.w);
    }
  }
  #pragma unroll
  for (int j = 0; j < 4; j++){
    int pair = i*BB + j0 + j;
    *(float4*)&out[((size_t)(pair*NQR + q))*D_MODEL + n4] = acc[j];
  }
}

// ---------------------------------------------------------------------------
extern "C" void kernel_launch(void* const* d_in, const int* in_sizes, int n_in,
                              void* d_out, int out_size, void* d_ws, size_t ws_size,
                              hipStream_t stream)
{
  const float* q_x    = (const float*)d_in[0];
  const float* kv_x   = (const float*)d_in[1];
  const float* ppe    = (const float*)d_in[2];
  const float* q_w    = (const float*)d_in[3];
  const float* q_b    = (const float*)d_in[4];
  const float* kv_w   = (const float*)d_in[5];
  const float* kv_b   = (const float*)d_in[6];
  const float* out_w  = (const float*)d_in[7];
  const float* out_b  = (const float*)d_in[8];
  const float* lnq_w  = (const float*)d_in[9];
  const float* lnq_b  = (const float*)d_in[10];
  const float* lnkv_w = (const float*)d_in[11];
  const float* lnkv_b = (const float*)d_in[12];
  float* out = (float*)d_out;

  float* ws    = (float*)d_ws;
  float* q_y   = ws;                              //  6144
  float* q_ln  = q_y  + NQR*D_MODEL;              //  6144
  float* Abuf_f = q_ln + NQR*D_MODEL;             //  3,686,400 (3200*2304 bf16)
  float* Wbuf_f = Abuf_f + (size_t)MPAD*KTOT/2;   //    884,736 (768*2304 bf16)
  float* C0    = Wbuf_f + (size_t)D_MODEL*KTOT/2; //  3x 2,420,736
  float* C1    = C0 + (size_t)MKV*D_MODEL;
  float* C2    = C1 + (size_t)MKV*D_MODEL;

  __hip_bfloat16* Abuf = (__hip_bfloat16*)Abuf_f;
  __hip_bfloat16* Wbuf = (__hip_bfloat16*)Wbuf_f;

  float* kv_ln = Abuf_f;                          // alias
  // Wbuf region (884,736 floats): zC 6144 + UC 393,216 + z1/z2 2x1536
  float* zC    = Wbuf_f;
  float* UC    = zC + 2*NIDX;
  float* z1    = UC + (size_t)2*NIDX*64;
  float* z2    = z1 + BB*NHEADS*NQR;
  float* p1    = C0;                              // alias
  float* p2    = p1 + (size_t)BB*NHEADS*NQR*D_MODEL;

  prep_kernel<<<MPAD + D_MODEL + 128, 192, 0, stream>>>(
      kv_x, kv_w, Abuf, Wbuf, q_x, q_w, q_y);

  gemm_mfma_kernel<<<dim3(MPAD/BM, D_MODEL/BN, KSPLIT), 256, 0, stream>>>(
      Abuf, Wbuf, C0);

  ln_all_kernel<<<MKV + NQR, 256, 0, stream>>>(
      C0, C1, C2, kv_b, lnkv_w, lnkv_b, kv_ln,
      q_y, q_b, lnq_w, lnq_b, q_ln);

  rank_chunk_kernel<<<dim3(BB, NHEADS, 4), 256, 0, stream>>>(
      kv_ln, q_ln, ppe, zC, UC);

  merge_proj_kernel<<<dim3(BB, NHEADS, 2), 256, 0, stream>>>(
      zC, UC, out_w, z1, z2, p1, p2);

  combine_out_kernel<<<dim3(BB, NQR, 4), 192, 0, stream>>>(
      z1, z2, p1, p2, out_b, out);
}

// Round 13
// 158.849 us; speedup vs baseline: 2.4953x; 1.0874x over previous
//
#include <hip/hip_runtime.h>
#include <hip/hip_bf16.h>
#include <math.h>

#define D_MODEL 768
#define NHEADS  12
#define DHEAD   64
#define NQR     8     // query rows
#define BB      16    // batch (ranks)
#define PP      197   // tokens per rank
#define NPAIR   256   // BB*BB
#define MKV     (BB*PP)     // 3152
#define LN_EPSF 1e-5f
#define SCALEF  0.125f      // 64^-0.5

// split-bf16 K-extended GEMM params
#define KTOT  2304          // 3*768:  [a_hi|a_hi|a_lo] x [w_hi|w_lo|w_hi]
#define KSPLIT 3
#define KPER  (KTOT/KSPLIT) // 768
#define MPAD  3200          // 25*128
#define BM 128
#define BN 128
#define BK 64

#define CH0   100           // chunk 0: p in [0,100)
#define CH1   97            // chunk 1: p in [100,197)
#define CHMAX 100
#define NIDX  (BB*NHEADS*2*NQR)   // 3072 (r,h,half,q) slots
#define NTTILE 144          // 12x12 64x64 transpose tiles

typedef __attribute__((ext_vector_type(8))) short short8v;   // 8 bf16
typedef __attribute__((ext_vector_type(4))) float float4v;   // mfma acc

__device__ __forceinline__ void gload16(const void* g, void* l){
  __builtin_amdgcn_global_load_lds(
      (const __attribute__((address_space(1))) unsigned int*)g,
      (__attribute__((address_space(3))) unsigned int*)l, 16, 0, 0);
}

__device__ __forceinline__ float lane_bcast(float v, int src){
  return __int_as_float(__builtin_amdgcn_readlane(__float_as_int(v), src));
}

// ---------------------------------------------------------------------------
// prep: fused pack + q GEMM + out_w transpose.
// blocks [0, MPAD)                 : pack kv_x row -> Ab  [hi, hi, lo]
// blocks [MPAD, MPAD+768)          : pack kv_w row -> Wb  [hi, lo, hi]
// blocks [MPAD+768, +128)          : q GEMM, 6 cols/block x 32 lanes/col
// blocks [MPAD+768+128, +144)      : 64x64 LDS-tiled transpose ow -> owT
//   owT[(h*64+d)*768 + n] = ow[n*768 + h*64+d]   (coalesced merge_proj reads)
// ---------------------------------------------------------------------------
__global__ __launch_bounds__(192) void prep_kernel(
    const float* __restrict__ kvx, const float* __restrict__ kvw,
    __hip_bfloat16* __restrict__ Ab, __hip_bfloat16* __restrict__ Wb,
    const float* __restrict__ qx, const float* __restrict__ qw,
    float* __restrict__ qy,
    const float* __restrict__ ow, float* __restrict__ owT)
{
  __shared__ float sbuf[NQR*D_MODEL];   // 24 KB, reused by q-gemm & transpose
  int b = blockIdx.x, t = threadIdx.x;
  if (b < MPAD + D_MODEL){
    const float* X; __hip_bfloat16* Y; int valid, mode, m;
    if (b < MPAD){ X = kvx; Y = Ab; valid = MKV;     mode = 0; m = b; }
    else         { X = kvw; Y = Wb; valid = D_MODEL; mode = 1; m = b - MPAD; }
    int k = t*4;
    float4 v = (m < valid) ? *(const float4*)&X[(size_t)m*D_MODEL + k]
                           : make_float4(0.f,0.f,0.f,0.f);
    float xsv[4] = {v.x, v.y, v.z, v.w};
    unsigned short hu[4], lu[4];
    #pragma unroll
    for (int i = 0; i < 4; i++){
      __hip_bfloat16 h = __float2bfloat16(xsv[i]);
      float hf = __bfloat162float(h);
      __hip_bfloat16 l = __float2bfloat16(xsv[i] - hf);
      hu[i] = *(unsigned short*)&h;
      lu[i] = *(unsigned short*)&l;
    }
    ushort4 hv = {hu[0], hu[1], hu[2], hu[3]};
    ushort4 lv = {lu[0], lu[1], lu[2], lu[3]};
    ushort4* row = (ushort4*)(Y + (size_t)m*KTOT);
    int s = k >> 2;
    if (mode == 0){ row[s] = hv; row[s+192] = hv; row[s+384] = lv; }
    else          { row[s] = hv; row[s+192] = lv; row[s+384] = hv; }
    return;
  }
  if (b < MPAD + D_MODEL + 128){
    // ---- q GEMM: block covers 6 output cols, 32 lanes each ----
    int b2 = b - (MPAD + D_MODEL);
    for (int e = t*4; e < NQR*D_MODEL; e += 768)
      *(float4*)&sbuf[e] = *(const float4*)&qx[e];
    __syncthreads();
    int col = t >> 5, lane = t & 31;
    int c = b2*6 + col;
    const float* wr = qw + (size_t)c*D_MODEL;
    float acc[NQR] = {};
    for (int k = lane*4; k < D_MODEL; k += 128){
      float4 w4 = *(const float4*)&wr[k];
      #pragma unroll
      for (int q = 0; q < NQR; q++){
        float4 x4 = *(const float4*)&sbuf[q*D_MODEL + k];
        acc[q] += x4.x*w4.x + x4.y*w4.y + x4.z*w4.z + x4.w*w4.w;
      }
    }
    #pragma unroll
    for (int q = 0; q < NQR; q++){
      float a = acc[q];
      for (int off = 16; off >= 1; off >>= 1) a += __shfl_xor(a, off, 32);
      if (lane == 0) qy[q*D_MODEL + c] = a;
    }
    return;
  }
  // ---- transpose tile: ow[n][dg] -> owT[dg][n], 64x64 via LDS ----
  int b3 = b - (MPAD + D_MODEL + 128);        // 0..143
  int n0 = (b3 / 12) * 64, d0 = (b3 % 12) * 64;
  float (*T)[65] = (float(*)[65])sbuf;        // 64x65 = 16.6 KB of sbuf
  for (int e = t; e < 4096; e += 192){
    int nn = e >> 6, dd = e & 63;
    T[nn][dd] = ow[(size_t)(n0+nn)*D_MODEL + d0+dd];
  }
  __syncthreads();
  for (int e = t; e < 4096; e += 192){
    int dd = e >> 6, nn = e & 63;
    owT[(size_t)(d0+dd)*D_MODEL + n0+nn] = T[nn][dd];
  }
}

// ---------------------------------------------------------------------------
// bf16 MFMA GEMM: C[kt][m][n] partial over K-split (kt = 0..2).  (unchanged)
// ---------------------------------------------------------------------------
__global__ __launch_bounds__(256) void gemm_mfma_kernel(
    const __hip_bfloat16* __restrict__ Ab, const __hip_bfloat16* __restrict__ Wb,
    float* __restrict__ Cp)
{
  __shared__ __hip_bfloat16 As[BM*BK];   // 16 KB
  __shared__ __hip_bfloat16 Bs[BN*BK];   // 16 KB
  int tid = threadIdx.x;
  int wave = tid >> 6, lane = tid & 63;
  int m0 = blockIdx.x*BM, n0 = blockIdx.y*BN, kt = blockIdx.z;
  int wr = wave >> 1, wc = wave & 1;

  float4v acc[4][4];
  #pragma unroll
  for (int i = 0; i < 4; i++)
    #pragma unroll
    for (int j = 0; j < 4; j++)
      acc[i][j] = (float4v){0.f, 0.f, 0.f, 0.f};

  int sbase = wave*256;
  for (int st = 0; st < KPER/BK; ++st){
    int k0 = kt*KPER + st*BK;
    __syncthreads();
    #pragma unroll
    for (int i = 0; i < 4; i++){
      int s  = sbase + i*64 + lane;
      int r  = s >> 3, kg = s & 7;
      int kgg = kg ^ (r & 7);
      gload16(Ab + (size_t)(m0 + r)*KTOT + k0 + kgg*8, (char*)As + (size_t)s*16);
      gload16(Wb + (size_t)(n0 + r)*KTOT + k0 + kgg*8, (char*)Bs + (size_t)s*16);
    }
    __syncthreads();
    #pragma unroll
    for (int ks = 0; ks < 2; ks++){
      int kq = ks*4 + (lane >> 4);
      short8v af[4], bf[4];
      #pragma unroll
      for (int t = 0; t < 4; t++){
        int ar = wr*64 + t*16 + (lane & 15);
        int as_ = ar*8 + (kq ^ (ar & 7));
        af[t] = *(const short8v*)((const char*)As + (size_t)as_*16);
        int br = wc*64 + t*16 + (lane & 15);
        int bs_ = br*8 + (kq ^ (br & 7));
        bf[t] = *(const short8v*)((const char*)Bs + (size_t)bs_*16);
      }
      #pragma unroll
      for (int i = 0; i < 4; i++)
        #pragma unroll
        for (int j = 0; j < 4; j++)
          acc[i][j] = __builtin_amdgcn_mfma_f32_16x16x32_bf16(af[i], bf[j], acc[i][j], 0, 0, 0);
    }
  }

  float* C = Cp + (size_t)kt*MKV*D_MODEL;
  #pragma unroll
  for (int i = 0; i < 4; i++){
    int mb = m0 + wr*64 + i*16 + ((lane >> 4) << 2);
    #pragma unroll
    for (int j = 0; j < 4; j++){
      int n = n0 + wc*64 + j*16 + (lane & 15);
      #pragma unroll
      for (int r = 0; r < 4; r++){
        int m = mb + r;
        if (m < MKV) C[(size_t)m*D_MODEL + n] = acc[i][j][r];
      }
    }
  }
}

// ---------------------------------------------------------------------------
// ln_all: blocks [0,MKV) = kv rows, [MKV,MKV+8) = q rows.  (unchanged)
// ---------------------------------------------------------------------------
__global__ __launch_bounds__(256) void ln_all_kernel(
    const float* __restrict__ C0, const float* __restrict__ C1,
    const float* __restrict__ C2, const float* __restrict__ kv_b,
    const float* __restrict__ lnkv_w, const float* __restrict__ lnkv_b,
    float* __restrict__ kv_ln,
    const float* __restrict__ q_y, const float* __restrict__ q_b,
    const float* __restrict__ lnq_w, const float* __restrict__ lnq_b,
    float* __restrict__ q_ln)
{
  __shared__ float red[256], red2[256];
  int b = blockIdx.x, tid = threadIdx.x;
  const float *xa, *xb, *xc, *bias, *lw, *lb; float* outp; bool three;
  if (b < MKV){
    xa = C0 + (size_t)b*D_MODEL; xb = C1 + (size_t)b*D_MODEL;
    xc = C2 + (size_t)b*D_MODEL;
    bias = kv_b; lw = lnkv_w; lb = lnkv_b;
    outp = kv_ln + (size_t)b*D_MODEL; three = true;
  } else {
    int r = b - MKV;
    xa = q_y + (size_t)r*D_MODEL; xb = xa; xc = xa;
    bias = q_b; lw = lnq_w; lb = lnq_b;
    outp = q_ln + (size_t)r*D_MODEL; three = false;
  }
  float x0 = xa[tid      ] + (three ? xb[tid      ] + xc[tid      ] : 0.f) + bias[tid      ];
  float x1 = xa[tid + 256] + (three ? xb[tid + 256] + xc[tid + 256] : 0.f) + bias[tid + 256];
  float x2 = xa[tid + 512] + (three ? xb[tid + 512] + xc[tid + 512] : 0.f) + bias[tid + 512];
  red[tid] = x0 + x1 + x2; red2[tid] = x0*x0 + x1*x1 + x2*x2;
  __syncthreads();
  for (int st = 128; st > 0; st >>= 1){
    if (tid < st){ red[tid] += red[tid+st]; red2[tid] += red2[tid+st]; }
    __syncthreads();
  }
  float mean = red[0]*(1.f/768.f);
  float var  = red2[0]*(1.f/768.f) - mean*mean;
  float inv  = rsqrtf(var + LN_EPSF);
  outp[tid      ] = (x0-mean)*inv*lw[tid      ] + lb[tid      ];
  outp[tid + 256] = (x1-mean)*inv*lw[tid + 256] + lb[tid + 256];
  outp[tid + 512] = (x2-mean)*inv*lw[tid + 512] + lb[tid + 512];
}

// ---------------------------------------------------------------------------
// rank_chunk: (unchanged from R12 — 96-VGPR class, no spill)
// ---------------------------------------------------------------------------
__global__ __launch_bounds__(256) void rank_chunk_kernel(
    const float* __restrict__ kv_ln, const float* __restrict__ q_ln,
    const float* __restrict__ ppe,
    float* __restrict__ zC, float* __restrict__ UC)
{
  __shared__ float A[CHMAX*65];    // 26 KB, stride 65 (conflict-free)
  int r = blockIdx.x, h = blockIdx.y;
  int half = blockIdx.z >> 1, c = blockIdx.z & 1;
  int p0 = c ? CH0 : 0;
  int np = c ? CH1 : CH0;
  int tid = threadIdx.x;
  int wave = tid >> 6, lane = tid & 63;
  int qa = 2*wave, qb = qa + 1;
  const float* qrowA = q_ln + (size_t)qa*D_MODEL + h*64;
  const float* qrowB = q_ln + (size_t)qb*D_MODEL + h*64;

  for (int e = tid; e < np*16; e += 256){
    int p = e >> 4, dq = (e & 15) << 2;
    float4 a = *(const float4*)&kv_ln[((size_t)(r*PP + p0 + p))*D_MODEL + h*64 + dq];
    float4 b = *(const float4*)&ppe[((size_t)(half*PP + p0 + p))*D_MODEL + h*64 + dq];
    float* rw = &A[p*65 + dq];
    rw[0] = a.x + b.x; rw[1] = a.y + b.y;
    rw[2] = a.z + b.z; rw[3] = a.w + b.w;
  }
  __syncthreads();

  int p1v = lane + 64;
  bool v1 = p1v < np;
  int p1c = v1 ? p1v : 0;
  float s0a = 0.f, s0b = 0.f, s1a = 0.f, s1b = 0.f;
  for (int d = 0; d < 64; d++){
    float qva = qrowA[d];
    float qvb = qrowB[d];
    float a0 = A[lane*65 + d];
    float a1 = A[p1c*65 + d];
    s0a += qva*a0; s1a += qva*a1;
    s0b += qvb*a0; s1b += qvb*a1;
  }
  float e0a = __expf(s0a*SCALEF);
  float e0b = __expf(s0b*SCALEF);
  float e1a = v1 ? __expf(s1a*SCALEF) : 0.f;
  float e1b = v1 ? __expf(s1b*SCALEF) : 0.f;
  float za = e0a + e1a;
  float zb = e0b + e1b;

  float ua = 0.f, ub = 0.f;
  for (int p = 0; p < 64; p++){
    float av = A[p*65 + lane];
    ua += lane_bcast(e0a, p) * av;
    ub += lane_bcast(e0b, p) * av;
  }
  for (int p = 64; p < np; p++){
    float av = A[p*65 + lane];
    ua += lane_bcast(e1a, p - 64) * av;
    ub += lane_bcast(e1b, p - 64) * av;
  }

  for (int off = 32; off >= 1; off >>= 1){
    za += __shfl_xor(za, off);
    zb += __shfl_xor(zb, off);
  }
  int idxa = ((r*NHEADS + h)*2 + half)*NQR + qa;
  int idxb = idxa + 1;
  if (lane == 0){
    zC[c*NIDX + idxa] = za;
    zC[c*NIDX + idxb] = zb;
  }
  UC[((size_t)(c*NIDX + idxa))*64 + lane] = ua;
  UC[((size_t)(c*NIDX + idxb))*64 + lane] = ub;
}

// ---------------------------------------------------------------------------
// merge_proj v2: U = U_c0 + U_c1; projection via TRANSPOSED weights owT:
//   per d: w = owT[h*64+d][n] (lane-consecutive -> coalesced), u broadcast
//   from registers via readlane (VALU; LDS nearly eliminated).
// grid (16, 12, 2), 256 thr.
// ---------------------------------------------------------------------------
__global__ __launch_bounds__(256) void merge_proj_kernel(
    const float* __restrict__ zC, const float* __restrict__ UC,
    const float* __restrict__ owT,
    float* __restrict__ z1O, float* __restrict__ z2O,
    float* __restrict__ p1, float* __restrict__ p2)
{
  __shared__ float Us[NQR*64];
  int r = blockIdx.x, h = blockIdx.y, half = blockIdx.z;
  int tid = threadIdx.x;
  int lane = tid & 63;
  int base = ((r*NHEADS + h)*2 + half)*NQR;

  for (int e = tid; e < NQR*64; e += 256)
    Us[e] = UC[(size_t)base*64 + e] + UC[((size_t)NIDX + base)*64 + e];
  if (tid < NQR){
    float z = zC[base + tid] + zC[NIDX + base + tid];
    float* zO = half ? z2O : z1O;
    zO[(r*NHEADS + h)*NQR + tid] = z;
  }
  __syncthreads();

  float um[NQR];
  #pragma unroll
  for (int m = 0; m < NQR; m++) um[m] = Us[m*64 + lane];

  float acc[NQR][3];
  #pragma unroll
  for (int m = 0; m < NQR; m++){ acc[m][0]=0.f; acc[m][1]=0.f; acc[m][2]=0.f; }
  const float* owTh = owT + (size_t)h*64*D_MODEL;
  for (int d = 0; d < 64; d++){
    float w0 = owTh[(size_t)d*D_MODEL + tid      ];
    float w1 = owTh[(size_t)d*D_MODEL + tid + 256];
    float w2 = owTh[(size_t)d*D_MODEL + tid + 512];
    #pragma unroll
    for (int m = 0; m < NQR; m++){
      float u = lane_bcast(um[m], d);   // SGPR-indexed readlane (d uniform)
      acc[m][0] += u*w0; acc[m][1] += u*w1; acc[m][2] += u*w2;
    }
  }
  float* P = half ? p2 : p1;
  #pragma unroll
  for (int m = 0; m < NQR; m++){
    size_t obase = (((size_t)r*NHEADS + h)*NQR + m)*D_MODEL;
    #pragma unroll
    for (int j = 0; j < 3; j++)
      P[obase + tid + 256*j] = acc[m][j];
  }
}

// ---------------------------------------------------------------------------
// Final combine: grid (i=16, q=8, jq=4), 192 thr; 4 j's per block. (unchanged)
// ---------------------------------------------------------------------------
__global__ __launch_bounds__(192) void combine_out_kernel(
    const float* __restrict__ z1, const float* __restrict__ z2,
    const float* __restrict__ p1, const float* __restrict__ p2,
    const float* __restrict__ out_b, float* __restrict__ out)
{
  __shared__ float cs[4][NHEADS];
  int i = blockIdx.x, q = blockIdx.y, jq = blockIdx.z;
  int j0 = jq*4;
  int tid = threadIdx.x;
  if (tid < 4*NHEADS){
    int j = tid / NHEADS, h = tid % NHEADS;
    int ii = (i*NHEADS + h)*NQR + q;
    int jj = ((j0 + j)*NHEADS + h)*NQR + q;
    cs[j][h] = 1.f / (z1[ii] + z2[jj]);
  }
  __syncthreads();

  int n4 = tid*4;
  float4 bv = *(const float4*)&out_b[n4];
  float4 acc[4];
  #pragma unroll
  for (int j = 0; j < 4; j++) acc[j] = bv;

  #pragma unroll
  for (int h = 0; h < NHEADS; h++){
    float4 a = *(const float4*)&p1[(((size_t)i*NHEADS + h)*NQR + q)*D_MODEL + n4];
    #pragma unroll
    for (int j = 0; j < 4; j++){
      float4 b = *(const float4*)&p2[(((size_t)(j0+j)*NHEADS + h)*NQR + q)*D_MODEL + n4];
      float c = cs[j][h];
      acc[j].x += c*(a.x - b.x);
      acc[j].y += c*(a.y - b.y);
      acc[j].z += c*(a.z - b.z);
      acc[j].w += c*(a.w - b.w);
    }
  }
  #pragma unroll
  for (int j = 0; j < 4; j++){
    int pair = i*BB + j0 + j;
    *(float4*)&out[((size_t)(pair*NQR + q))*D_MODEL + n4] = acc[j];
  }
}

// ---------------------------------------------------------------------------
extern "C" void kernel_launch(void* const* d_in, const int* in_sizes, int n_in,
                              void* d_out, int out_size, void* d_ws, size_t ws_size,
                              hipStream_t stream)
{
  const float* q_x    = (const float*)d_in[0];
  const float* kv_x   = (const float*)d_in[1];
  const float* ppe    = (const float*)d_in[2];
  const float* q_w    = (const float*)d_in[3];
  const float* q_b    = (const float*)d_in[4];
  const float* kv_w   = (const float*)d_in[5];
  const float* kv_b   = (const float*)d_in[6];
  const float* out_w  = (const float*)d_in[7];
  const float* out_b  = (const float*)d_in[8];
  const float* lnq_w  = (const float*)d_in[9];
  const float* lnq_b  = (const float*)d_in[10];
  const float* lnkv_w = (const float*)d_in[11];
  const float* lnkv_b = (const float*)d_in[12];
  float* out = (float*)d_out;

  float* ws    = (float*)d_ws;
  float* q_y   = ws;                              //  6144
  float* q_ln  = q_y  + NQR*D_MODEL;              //  6144
  float* Abuf_f = q_ln + NQR*D_MODEL;             //  3,686,400 (3200*2304 bf16)
  float* Wbuf_f = Abuf_f + (size_t)MPAD*KTOT/2;   //    884,736 (768*2304 bf16)
  float* C0    = Wbuf_f + (size_t)D_MODEL*KTOT/2; //  3x 2,420,736
  float* C1    = C0 + (size_t)MKV*D_MODEL;
  float* C2    = C1 + (size_t)MKV*D_MODEL;
  float* owT   = C2 + (size_t)MKV*D_MODEL;        //  589,824 (survives gemm/ln)

  __hip_bfloat16* Abuf = (__hip_bfloat16*)Abuf_f;
  __hip_bfloat16* Wbuf = (__hip_bfloat16*)Wbuf_f;

  float* kv_ln = Abuf_f;                          // alias
  // Wbuf region (884,736 floats): zC 6144 + UC 393,216 + z1/z2 2x1536
  float* zC    = Wbuf_f;
  float* UC    = zC + 2*NIDX;
  float* z1    = UC + (size_t)2*NIDX*64;
  float* z2    = z1 + BB*NHEADS*NQR;
  float* p1    = C0;                              // alias
  float* p2    = p1 + (size_t)BB*NHEADS*NQR*D_MODEL;

  prep_kernel<<<MPAD + D_MODEL + 128 + NTTILE, 192, 0, stream>>>(
      kv_x, kv_w, Abuf, Wbuf, q_x, q_w, q_y, out_w, owT);

  gemm_mfma_kernel<<<dim3(MPAD/BM, D_MODEL/BN, KSPLIT), 256, 0, stream>>>(
      Abuf, Wbuf, C0);

  ln_all_kernel<<<MKV + NQR, 256, 0, stream>>>(
      C0, C1, C2, kv_b, lnkv_w, lnkv_b, kv_ln,
      q_y, q_b, lnq_w, lnq_b, q_ln);

  rank_chunk_kernel<<<dim3(BB, NHEADS, 4), 256, 0, stream>>>(
      kv_ln, q_ln, ppe, zC, UC);

  merge_proj_kernel<<<dim3(BB, NHEADS, 2), 256, 0, stream>>>(
      zC, UC, owT, z1, z2, p1, p2);

  combine_out_kernel<<<dim3(BB, NQR, 4), 192, 0, stream>>>(
      z1, z2, p1, p2, out_b, out);
}